// Round 11
// baseline (188.649 us; speedup 1.0000x reference)
//
#include <hip/hip_runtime.h>

typedef __attribute__((ext_vector_type(8))) short short8;   // 8 bf16 (MFMA A/B frag)
typedef __attribute__((ext_vector_type(4))) float f32x4;

#define SDIM 32
#define HDIM 34
#define NEXP 12
#define ACOL 256
#define SPB  256
#define NT   (SPB / 16)
#define SLAB 68

// fp32 -> bf16 (round-to-nearest-ish), pack two into one dword
__device__ __forceinline__ unsigned int bpack(float lo, float hi) {
    unsigned int a = __builtin_bit_cast(unsigned int, lo);
    unsigned int b = __builtin_bit_cast(unsigned int, hi);
    return ((a + 0x8000u) >> 16) | ((b + 0x8000u) & 0xffff0000u);
}

// ---- k0: pack Wout into fragment-ordered bf16 records ----
// wpack[((e*4+wv)*4+j)*64 + lane] = 8 bf16 of W[col=wv*64+j*16+(lane&15)][k=8g..8g+7]
// w2b[e*256+col] = { bf16(W[col][32],W[col][33]), bf16(bias[col], 0) }
__global__ __launch_bounds__(256) void k0_wpack(
    const float* __restrict__ Wout, const float* __restrict__ bout,
    uint4* __restrict__ wpack, uint2* __restrict__ w2b)
{
    const int tid = blockIdx.x * 256 + threadIdx.x;
    if (tid < NEXP * 4 * 4 * 64) {
        const int lane = tid & 63;
        const int j    = (tid >> 6) & 3;
        const int wvv  = (tid >> 8) & 3;
        const int e    = tid >> 10;
        const int r = lane & 15, g = lane >> 4;
        const int col = wvv * 64 + j * 16 + r;
        const float* wr = Wout + ((size_t)e * ACOL + col) * HDIM;
        uint4 q;
        q.x = bpack(wr[g*8+0], wr[g*8+1]);
        q.y = bpack(wr[g*8+2], wr[g*8+3]);
        q.z = bpack(wr[g*8+4], wr[g*8+5]);
        q.w = bpack(wr[g*8+6], wr[g*8+7]);
        wpack[tid] = q;
    }
    if (tid < NEXP * ACOL) {
        const float* wr2 = Wout + (size_t)tid * HDIM;
        w2b[tid] = make_uint2(bpack(wr2[32], wr2[33]), bpack(bout[tid], 0.0f));
    }
}

__global__ __launch_bounds__(256, 4) void actor_kernel(
    const float* __restrict__ states,
    const int*   __restrict__ epoch_idx,
    const float* __restrict__ W1,
    const float* __restrict__ b1,
    const uint4* __restrict__ wpack,
    const uint2* __restrict__ w2b,
    const int*   __restrict__ mask,
    float*       __restrict__ out,
    int nB)
{
    // xs: 64 B/row, bf16 k0..31 in 4 16B chunks, chunk c at (c ^ ((row>>2)&3)).
    __shared__ __align__(16) unsigned int xs[SPB * 16];     // 16384 B
    __shared__ uint2        xt2[SPB];                       // 2048 B {x32x33, 1.0}
    __shared__ int          expl[SPB];                      // 1024 B
    __shared__ unsigned int tmask[NT];                      // 64 B presence masks
    __shared__ __align__(16) float slab[4][16 * SLAB];      // 17408 B private slabs
    // total ~36.9 KB -> 4 blocks/CU

    float* w1s = &slab[0][0];            // aliased: phases 0-1 only (1122 floats)
    float* b1s = w1s + HDIM * SDIM;

    const int t  = threadIdx.x;
    const int s0 = blockIdx.x * SPB;

    // ---- phase 0: stage W1/b1, zero tile masks ----
    for (int i = t; i < HDIM * SDIM; i += 256) w1s[i] = W1[i];
    if (t < HDIM) b1s[t] = b1[t];
    if (t < NT) tmask[t] = 0u;

    const int  sidx  = s0 + t;
    const bool valid = (sidx < nB);
    float sr[SDIM];
    int e = 0;
    if (valid) {
        const f32x4* sp = (const f32x4*)(states + (size_t)sidx * SDIM);
        #pragma unroll
        for (int q = 0; q < SDIM / 4; ++q) {
            f32x4 v = sp[q];
            sr[4*q+0] = v[0]; sr[4*q+1] = v[1]; sr[4*q+2] = v[2]; sr[4*q+3] = v[3];
        }
        e = epoch_idx[sidx];
    }
    __syncthreads();                 // w1s staged, tmask zeroed

    if (valid) atomicOr(&tmask[t >> 4], 1u << e);
    expl[t] = valid ? e : 64;

    // ---- phase 1: trunk GEMV ----
    float x[HDIM];
    if (valid) {
        #pragma unroll 2
        for (int h = 0; h < HDIM; ++h) {
            float acc = b1s[h];
            const float4* wr = (const float4*)(w1s + h * SDIM);
            #pragma unroll
            for (int q = 0; q < SDIM / 4; ++q) {
                float4 wv = wr[q];
                acc = fmaf(sr[4*q+0], wv.x, acc);
                acc = fmaf(sr[4*q+1], wv.y, acc);
                acc = fmaf(sr[4*q+2], wv.z, acc);
                acc = fmaf(sr[4*q+3], wv.w, acc);
            }
            x[h] = fmaxf(acc, 0.0f);
        }
    }

    // ---- phase 2: write bf16 x row (natural order, swizzled chunks) ----
    if (valid) {
        unsigned d[17];
        #pragma unroll
        for (int k = 0; k < 17; ++k) d[k] = bpack(x[2*k], x[2*k+1]);
        const unsigned sw = ((unsigned)t >> 2) & 3u;
        char* rbase = (char*)xs + t * 64;
        #pragma unroll
        for (int c = 0; c < 4; ++c) {
            f32x4 q;
            q[0] = __builtin_bit_cast(float, d[4*c+0]);
            q[1] = __builtin_bit_cast(float, d[4*c+1]);
            q[2] = __builtin_bit_cast(float, d[4*c+2]);
            q[3] = __builtin_bit_cast(float, d[4*c+3]);
            *(f32x4*)(rbase + ((unsigned)(c ^ sw) << 4)) = q;
        }
        xt2[t] = make_uint2(d[16], bpack(1.0f, 0.0f));   // k32,33 | k34=1.0
    }
    __syncthreads();                 // xs/xt2/expl/tmask visible — LAST barrier

    // ---- phase 3: barrier-free expert-masked MFMA over natural tiles ----
    const int wv   = t >> 6;
    const int lane = t & 63;
    const int r    = lane & 15;
    const int g    = lane >> 4;
    const int m    = mask[wv * 64 + lane];
    const float NEG = -1e9f;
    float* mystg = slab[wv];
    float* outw  = out + (size_t)s0 * ACOL + wv * 64 + lane;
    const short8 z8 = __builtin_bit_cast(short8, make_uint4(0u, 0u, 0u, 0u));

    for (int tile = 0; tile < NT; ++tile) {
        const int rb  = tile << 4;
        const int row = rb + r;
        const char* rp = (const char*)xs + row * 64;
        short8 a1 = *(const short8*)(rp + ((((unsigned)g ^ (((unsigned)row >> 2) & 3u))) << 4));
        const uint2 x2 = xt2[row];
        const short8 at = (g == 0)
            ? __builtin_bit_cast(short8, make_uint4(x2.x, x2.y, 0u, 0u)) : z8;
        const int er = expl[row];
        unsigned pm = tmask[tile];

        f32x4 acc[4];
        #pragma unroll
        for (int j = 0; j < 4; ++j) acc[j] = f32x4{0.f, 0.f, 0.f, 0.f};

        if (pm) {
            int e2 = (int)__builtin_ctz(pm); pm &= pm - 1;
            const uint4* wp = wpack + ((size_t)(e2 * 4 + wv) * 4) * 64 + lane;
            uint4 fc0 = wp[0], fc1 = wp[64], fc2 = wp[128], fc3 = wp[192];
            const uint2* tb = w2b + e2 * ACOL + wv * 64 + r;
            uint2 tc0 = tb[0], tc1 = tb[16], tc2 = tb[32], tc3 = tb[48];

            while (true) {
                int en = -1;
                uint4 fn0, fn1, fn2, fn3; uint2 tn0, tn1, tn2, tn3;
                if (pm) {                       // prefetch next expert's fragments
                    en = (int)__builtin_ctz(pm); pm &= pm - 1;
                    const uint4* wpn = wpack + ((size_t)(en * 4 + wv) * 4) * 64 + lane;
                    fn0 = wpn[0]; fn1 = wpn[64]; fn2 = wpn[128]; fn3 = wpn[192];
                    const uint2* tbn = w2b + en * ACOL + wv * 64 + r;
                    tn0 = tbn[0]; tn1 = tbn[16]; tn2 = tbn[32]; tn3 = tbn[48];
                }
                const bool mt = (er == e2);
                const short8 a1m = mt ? a1 : z8;
                const short8 a2m = mt ? at : z8;
                acc[0] = __builtin_amdgcn_mfma_f32_16x16x32_bf16(a1m, __builtin_bit_cast(short8, fc0), acc[0], 0, 0, 0);
                acc[0] = __builtin_amdgcn_mfma_f32_16x16x32_bf16(a2m, __builtin_bit_cast(short8, make_uint4(tc0.x, tc0.y, 0u, 0u)), acc[0], 0, 0, 0);
                acc[1] = __builtin_amdgcn_mfma_f32_16x16x32_bf16(a1m, __builtin_bit_cast(short8, fc1), acc[1], 0, 0, 0);
                acc[1] = __builtin_amdgcn_mfma_f32_16x16x32_bf16(a2m, __builtin_bit_cast(short8, make_uint4(tc1.x, tc1.y, 0u, 0u)), acc[1], 0, 0, 0);
                acc[2] = __builtin_amdgcn_mfma_f32_16x16x32_bf16(a1m, __builtin_bit_cast(short8, fc2), acc[2], 0, 0, 0);
                acc[2] = __builtin_amdgcn_mfma_f32_16x16x32_bf16(a2m, __builtin_bit_cast(short8, make_uint4(tc2.x, tc2.y, 0u, 0u)), acc[2], 0, 0, 0);
                acc[3] = __builtin_amdgcn_mfma_f32_16x16x32_bf16(a1m, __builtin_bit_cast(short8, fc3), acc[3], 0, 0, 0);
                acc[3] = __builtin_amdgcn_mfma_f32_16x16x32_bf16(a2m, __builtin_bit_cast(short8, make_uint4(tc3.x, tc3.y, 0u, 0u)), acc[3], 0, 0, 0);
                if (en < 0) break;
                e2 = en;
                fc0 = fn0; fc1 = fn1; fc2 = fn2; fc3 = fn3;
                tc0 = tn0; tc1 = tn1; tc2 = tn2; tc3 = tn3;
            }
        }

        // private slab transpose (in-order DS, no barrier)
        #pragma unroll
        for (int j = 0; j < 4; ++j) {
            #pragma unroll
            for (int i = 0; i < 4; ++i)
                mystg[(4 * g + i) * SLAB + 16 * j + r] = acc[j][i];
        }
        // sequential 256B stores: 4 waves jointly cover contiguous 16KB
        #pragma unroll
        for (int lrow = 0; lrow < 16; ++lrow) {
            float v = mystg[lrow * SLAB + lane];
            v = m ? v : NEG;
            if (s0 + rb + lrow < nB)
                outw[(size_t)(rb + lrow) * ACOL] = v;
        }
    }
}

extern "C" void kernel_launch(void* const* d_in, const int* in_sizes, int n_in,
                              void* d_out, int out_size, void* d_ws, size_t ws_size,
                              hipStream_t stream) {
    const float* states    = (const float*)d_in[0];
    const int*   epoch_idx = (const int*)  d_in[1];
    const float* W1        = (const float*)d_in[2];
    const float* b1        = (const float*)d_in[3];
    const float* Wout      = (const float*)d_in[4];
    const float* bout      = (const float*)d_in[5];
    const int*   mask      = (const int*)  d_in[6];
    float*       out       = (float*)d_out;

    const int nB   = in_sizes[0] / SDIM;
    const int grid = (nB + SPB - 1) / SPB;

    uint4* wpack = (uint4*)d_ws;                                // 196608 B
    uint2* w2b   = (uint2*)((char*)d_ws + 196608);              // 24576 B

    k0_wpack<<<48, 256, 0, stream>>>(Wout, bout, wpack, w2b);
    actor_kernel<<<grid, 256, 0, stream>>>(states, epoch_idx, W1, b1,
                                           wpack, w2b, mask, out, nB);
}

// Round 12
// 137.809 us; speedup vs baseline: 1.3689x; 1.3689x over previous
//
#include <hip/hip_runtime.h>

typedef __attribute__((ext_vector_type(8))) short short8;   // 8 bf16 (MFMA A/B frag)
typedef __attribute__((ext_vector_type(4))) float f32x4;

#define SDIM 32
#define HDIM 34
#define NEXP 12
#define ACOL 256
#define SPB  256
#define MAXROWS 448        // max padded rows = 256 + 12*15 = 436
#define MAXT    28         // max tiles
#define SLAB    68         // per-wave quarter-slab stride (64+4)

// fp32 -> bf16 (round-to-nearest-ish), pack two into one dword
__device__ __forceinline__ unsigned int bpack(float lo, float hi) {
    unsigned int a = __builtin_bit_cast(unsigned int, lo);
    unsigned int b = __builtin_bit_cast(unsigned int, hi);
    return ((a + 0x8000u) >> 16) | ((b + 0x8000u) & 0xffff0000u);
}

// ---- k0: pack Wout into fragment-ordered bf16 + {k32k33, bias} records ----
// wpack[(e*16+j)*64 + lane] = 8 bf16 of W[col=16j+(lane&15)][k=8g..8g+7], g=lane>>4
// w2b[e*256+col] = { bf16(W[col][32],W[col][33]), bf16(bias[col], 0) }
__global__ __launch_bounds__(256) void k0_wpack(
    const float* __restrict__ Wout, const float* __restrict__ bout,
    uint4* __restrict__ wpack, uint2* __restrict__ w2b)
{
    const int tid = blockIdx.x * 256 + threadIdx.x;
    if (tid < NEXP * 16 * 64) {
        const int lane = tid & 63;
        const int j    = (tid >> 6) & 15;
        const int e    = tid >> 10;
        const int r = lane & 15, g = lane >> 4;
        const int col = j * 16 + r;
        const float* wr = Wout + ((size_t)e * ACOL + col) * HDIM;
        uint4 q;
        q.x = bpack(wr[g*8+0], wr[g*8+1]);
        q.y = bpack(wr[g*8+2], wr[g*8+3]);
        q.z = bpack(wr[g*8+4], wr[g*8+5]);
        q.w = bpack(wr[g*8+6], wr[g*8+7]);
        wpack[tid] = q;
    }
    if (tid < NEXP * ACOL) {
        const float* wr2 = Wout + (size_t)tid * HDIM;
        w2b[tid] = make_uint2(bpack(wr2[32], wr2[33]), bpack(bout[tid], 0.0f));
    }
}

__global__ __launch_bounds__(256, 3) void actor_kernel(
    const float* __restrict__ states,
    const int*   __restrict__ epoch_idx,
    const float* __restrict__ W1,
    const float* __restrict__ b1,
    const uint4* __restrict__ wpack,
    const uint2* __restrict__ w2b,
    const int*   __restrict__ mask,
    float*       __restrict__ out,
    int nB)
{
    // xs: 64 B/row, bf16 k0..31 in 4 16B chunks, chunk c at (c ^ ((row>>2)&3)).
    __shared__ __align__(16) unsigned int xs[MAXROWS * 16];  // 28672 B
    __shared__ uint2          xt2[MAXROWS];                  // 3584 B {x32x33, 1.0}
    __shared__ unsigned short lrid[MAXROWS];                 // 896 B
    __shared__ __align__(16) float slab[4][16 * SLAB];       // 17408 B private slabs
    __shared__ int texp[32];                                 // tile -> expert
    __shared__ int cnt[NEXP], goff[NEXP], ntl[NEXP], ntt;
    // total ~51 KB -> 3 blocks/CU

    float* w1s = &slab[0][0];            // aliased: phases 0-1 only
    float* b1s = w1s + HDIM * SDIM;

    const int t  = threadIdx.x;
    const int s0 = blockIdx.x * SPB;

    // ---- phase 0 ----
    for (int i = t; i < HDIM * SDIM; i += 256) w1s[i] = W1[i];
    if (t < HDIM) b1s[t] = b1[t];
    if (t < NEXP) cnt[t] = 0;
    for (int i = t; i < MAXROWS; i += 256) lrid[i] = 0xFFFFu;

    const int  sidx  = s0 + t;
    const bool valid = (sidx < nB);
    float sr[SDIM];
    int e = 0;
    if (valid) {
        const f32x4* sp = (const f32x4*)(states + (size_t)sidx * SDIM);
        #pragma unroll
        for (int q = 0; q < SDIM / 4; ++q) {
            f32x4 v = sp[q];
            sr[4*q+0] = v[0]; sr[4*q+1] = v[1]; sr[4*q+2] = v[2]; sr[4*q+3] = v[3];
        }
        e = epoch_idx[sidx];
    }
    __syncthreads();                 // cnt zeroed, w1s staged

    int rank = 0;
    if (valid) rank = atomicAdd(&cnt[e], 1);
    __syncthreads();                 // cnt final

    if (t == 0) {
        int base = 0;
        #pragma unroll
        for (int i = 0; i < NEXP; ++i) {
            goff[i] = base;
            int nt = (cnt[i] + 15) >> 4;
            ntl[i] = nt;
            base += nt << 4;
        }
        ntt = base >> 4;
    }
    float x[HDIM];
    if (valid) {
        #pragma unroll 2
        for (int h = 0; h < HDIM; ++h) {
            float acc = b1s[h];
            const float4* wr = (const float4*)(w1s + h * SDIM);
            #pragma unroll
            for (int q = 0; q < SDIM / 4; ++q) {
                float4 wv = wr[q];
                acc = fmaf(sr[4*q+0], wv.x, acc);
                acc = fmaf(sr[4*q+1], wv.y, acc);
                acc = fmaf(sr[4*q+2], wv.z, acc);
                acc = fmaf(sr[4*q+3], wv.w, acc);
            }
            x[h] = fmaxf(acc, 0.0f);
        }
    }
    __syncthreads();                 // goff/ntl/ntt ready; w1s reads done

    if (t < NEXP) {                  // tile -> expert map
        const int tb = goff[t] >> 4;
        for (int k = 0; k < ntl[t]; ++k) texp[tb + k] = t;
    }
    if (valid) {                     // scatter bf16 x row into sorted slot
        const int slot = goff[e] + rank;
        const unsigned sw = (((unsigned)slot >> 2) & 3u);
        char* rbase = (char*)xs + slot * 64;
        unsigned d[17];
        #pragma unroll
        for (int k = 0; k < 17; ++k) d[k] = bpack(x[2*k], x[2*k+1]);
        #pragma unroll
        for (int c = 0; c < 4; ++c) {
            f32x4 q;
            q[0] = __builtin_bit_cast(float, d[4*c+0]);
            q[1] = __builtin_bit_cast(float, d[4*c+1]);
            q[2] = __builtin_bit_cast(float, d[4*c+2]);
            q[3] = __builtin_bit_cast(float, d[4*c+3]);
            *(f32x4*)(rbase + (((unsigned)c ^ sw) << 4)) = q;
        }
        xt2[slot]  = make_uint2(d[16], bpack(1.0f, 0.0f));  // k32,33 | k34=1
        lrid[slot] = (unsigned short)t;
    }
    __syncthreads();                 // LAST barrier in kernel

    // ---- phase 3: wave-private, barrier-free, dense-store main loop ----
    const int wv   = t >> 6;
    const int lane = t & 63;
    const int r    = lane & 15;
    const int g    = lane >> 4;
    const float NEG = -1e9f;
    float* mystg = slab[wv];
    float* outb  = out + (size_t)s0 * ACOL;
    const short8 z8 = __builtin_bit_cast(short8, make_uint4(0u, 0u, 0u, 0u));
    int mk[4];
    #pragma unroll
    for (int qp = 0; qp < 4; ++qp) mk[qp] = mask[qp * 64 + lane];

    const int nt_tot = ntt;
    const int t0 = (nt_tot * wv) >> 2;         // contiguous tile range per wave
    const int t1 = (nt_tot * (wv + 1)) >> 2;

    for (int tile = t0; tile < t1; ++tile) {
        const int e2 = texp[tile];
        const int rb = tile << 4;
        const int row = rb + r;
        const char* rp = (const char*)xs + row * 64;
        short8 a1 = *(const short8*)(rp +
                      ((((unsigned)g ^ (((unsigned)row >> 2) & 3u))) << 4));
        const uint2 x2 = xt2[row];
        const short8 a2 = (g == 0)
            ? __builtin_bit_cast(short8, make_uint4(x2.x, x2.y, 0u, 0u)) : z8;

        const uint4* wp  = wpack + ((size_t)e2 * 16) * 64 + lane;
        const uint2* tbp = w2b + e2 * ACOL + r;

        #pragma unroll
        for (int qp = 0; qp < 4; ++qp) {
            // compute 4 col-tiles (64 cols) of this quarter
            #pragma unroll
            for (int jj = 0; jj < 4; ++jj) {
                const int j = qp * 4 + jj;
                const uint4 f  = wp[j * 64];
                const uint2 tv = tbp[j * 16];
                f32x4 a = {0.f, 0.f, 0.f, 0.f};
                a = __builtin_amdgcn_mfma_f32_16x16x32_bf16(
                        a1, __builtin_bit_cast(short8, f), a, 0, 0, 0);
                const short8 b2 = (g == 0)
                    ? __builtin_bit_cast(short8, make_uint4(tv.x, tv.y, 0u, 0u)) : z8;
                a = __builtin_amdgcn_mfma_f32_16x16x32_bf16(a2, b2, a, 0, 0, 0);
                #pragma unroll
                for (int i = 0; i < 4; ++i)
                    mystg[(4 * g + i) * SLAB + jj * 16 + r] = a[i];
            }
            // read back + store this 64-col quarter: 16 x 256B contiguous
            const int cq = qp * 64;
            #pragma unroll
            for (int lrow = 0; lrow < 16; ++lrow) {
                const unsigned rid = lrid[rb + lrow];
                float v = mystg[lrow * SLAB + lane];
                v = mk[qp] ? v : NEG;
                if (rid != 0xFFFFu)
                    outb[(size_t)rid * ACOL + cq + lane] = v;
            }
        }
    }
}

extern "C" void kernel_launch(void* const* d_in, const int* in_sizes, int n_in,
                              void* d_out, int out_size, void* d_ws, size_t ws_size,
                              hipStream_t stream) {
    const float* states    = (const float*)d_in[0];
    const int*   epoch_idx = (const int*)  d_in[1];
    const float* W1        = (const float*)d_in[2];
    const float* b1        = (const float*)d_in[3];
    const float* Wout      = (const float*)d_in[4];
    const float* bout      = (const float*)d_in[5];
    const int*   mask      = (const int*)  d_in[6];
    float*       out       = (float*)d_out;

    const int nB   = in_sizes[0] / SDIM;
    const int grid = (nB + SPB - 1) / SPB;

    uint4* wpack = (uint4*)d_ws;                                // 196608 B
    uint2* w2b   = (uint2*)((char*)d_ws + 196608);              // 24576 B

    k0_wpack<<<48, 256, 0, stream>>>(Wout, bout, wpack, w2b);
    actor_kernel<<<grid, 256, 0, stream>>>(states, epoch_idx, W1, b1,
                                           wpack, w2b, mask, out, nB);
}

// Round 13
// 85.599 us; speedup vs baseline: 2.2039x; 1.6099x over previous
//
#include <hip/hip_runtime.h>

typedef __attribute__((ext_vector_type(8))) short short8;   // 8 bf16 (MFMA A/B frag)
typedef __attribute__((ext_vector_type(4))) float f32x4;
typedef __attribute__((ext_vector_type(4))) int   i32x4;

#define SDIM 32
#define HDIM 34
#define NEXP 12
#define ACOL 256
#define SPB  256
#define MAXROWS 448        // max padded rows = 256 + 12*15 = 436, round up
#define STGS 260           // bf16 staging stride (ushorts)

// raw barrier: waits LDS ops only, never drains global stores (T4)
#define BAR_LGKM() asm volatile("s_waitcnt lgkmcnt(0)\n\ts_barrier" ::: "memory")

// fp32 -> bf16 (round-to-nearest-ish), pack two into one dword
__device__ __forceinline__ unsigned int bpack(float lo, float hi) {
    unsigned int a = __builtin_bit_cast(unsigned int, lo);
    unsigned int b = __builtin_bit_cast(unsigned int, hi);
    return ((a + 0x8000u) >> 16) | ((b + 0x8000u) & 0xffff0000u);
}

// ---- k0: pack Wout into fragment-ordered bf16 records (R9 layout) ----
// wpack[((e*4+wv)*4+j)*64 + lane] = 8 bf16 of W[col=wv*64+j*16+(lane&15)][k=8g..8g+7]
__global__ __launch_bounds__(256) void k0_wpack(
    const float* __restrict__ Wout, uint4* __restrict__ wpack,
    unsigned int* __restrict__ w2p)
{
    const int tid = blockIdx.x * 256 + threadIdx.x;
    if (tid >= NEXP * 4 * 4 * 64) return;
    const int lane = tid & 63;
    const int j    = (tid >> 6) & 3;
    const int wvv  = (tid >> 8) & 3;
    const int e    = tid >> 10;
    const int r = lane & 15, g = lane >> 4;
    const int col = wvv * 64 + j * 16 + r;
    const float* wr = Wout + ((size_t)e * ACOL + col) * HDIM;
    uint4 q;
    q.x = bpack(wr[g*8+0], wr[g*8+1]);
    q.y = bpack(wr[g*8+2], wr[g*8+3]);
    q.z = bpack(wr[g*8+4], wr[g*8+5]);
    q.w = bpack(wr[g*8+6], wr[g*8+7]);
    wpack[tid] = q;
    if (tid < NEXP * ACOL) {                       // w2: k=32,33 per (e,col)
        const float* wr2 = Wout + (size_t)tid * HDIM;
        w2p[tid] = bpack(wr2[32], wr2[33]);
    }
}

__global__ __launch_bounds__(256, 4) void actor_kernel(
    const float* __restrict__ states,
    const int*   __restrict__ epoch_idx,
    const float* __restrict__ W1,
    const float* __restrict__ b1,
    const uint4* __restrict__ wpack,
    const unsigned int* __restrict__ w2p,
    const float* __restrict__ bout,
    const int*   __restrict__ mask,
    float*       __restrict__ out,
    int nB)
{
    // xs: 64 B/row = bf16 k0..31 in 4 16B chunks, chunk c at (c ^ ((row>>2)&3)).
    __shared__ __align__(16) unsigned int xs[MAXROWS * 16];      // 28672 B
    __shared__ unsigned int   xt[MAXROWS];                       // 1792 B (k32,33)
    __shared__ unsigned short rowid[MAXROWS];                    // 896 B
    __shared__ __align__(8) unsigned short stgb[16 * STGS];      // 8320 B bf16 staging
    __shared__ int cnt[NEXP], goff[NEXP], ntl[NEXP];
    // total ~39.9 KB -> 4 blocks/CU (16 waves)

    float* w1s = (float*)stgb;           // aliased: phases 0-1 only (4488 B)
    float* b1s = w1s + HDIM * SDIM;

    const int t  = threadIdx.x;
    const int s0 = blockIdx.x * SPB;

    // ---- phase 0 ----
    for (int i = t; i < HDIM * SDIM; i += 256) w1s[i] = W1[i];
    if (t < HDIM) b1s[t] = b1[t];
    if (t < NEXP) cnt[t] = 0;
    for (int i = t; i < MAXROWS; i += 256) rowid[i] = 0xFFFFu;

    const int  sidx  = s0 + t;
    const bool valid = (sidx < nB);
    float sr[SDIM];
    int e = 0;
    if (valid) {
        const f32x4* sp = (const f32x4*)(states + (size_t)sidx * SDIM);
        #pragma unroll
        for (int q = 0; q < SDIM / 4; ++q) {
            f32x4 v = sp[q];
            sr[4*q+0] = v[0]; sr[4*q+1] = v[1]; sr[4*q+2] = v[2]; sr[4*q+3] = v[3];
        }
        e = epoch_idx[sidx];
    }
    __syncthreads();                 // cnt zeroed, w1s staged

    int rank = 0;
    if (valid) rank = atomicAdd(&cnt[e], 1);
    __syncthreads();                 // cnt final

    if (t == 0) {
        int base = 0;
        #pragma unroll
        for (int i = 0; i < NEXP; ++i) {
            goff[i] = base;
            int nt = (cnt[i] + 15) >> 4;
            ntl[i] = nt;
            base += nt << 4;
        }
    }
    float x[HDIM];
    if (valid) {
        #pragma unroll 2
        for (int h = 0; h < HDIM; ++h) {
            float acc = b1s[h];
            const float4* wr = (const float4*)(w1s + h * SDIM);
            #pragma unroll
            for (int q = 0; q < SDIM / 4; ++q) {
                float4 wv = wr[q];
                acc = fmaf(sr[4*q+0], wv.x, acc);
                acc = fmaf(sr[4*q+1], wv.y, acc);
                acc = fmaf(sr[4*q+2], wv.z, acc);
                acc = fmaf(sr[4*q+3], wv.w, acc);
            }
            x[h] = fmaxf(acc, 0.0f);
        }
    }
    __syncthreads();                 // goff ready; w1s reads done

    // ---- phase 2: scatter bf16 x row into sorted+padded slot (swizzled) ----
    if (valid) {
        const int slot = goff[e] + rank;
        const unsigned sw = (((unsigned)slot >> 2) & 3u) << 4;
        char* rbase = (char*)xs + slot * 64;
        unsigned d[17];
        #pragma unroll
        for (int k = 0; k < 17; ++k) d[k] = bpack(x[2*k], x[2*k+1]);
        #pragma unroll
        for (int c = 0; c < 4; ++c) {
            f32x4 q;
            q[0] = __builtin_bit_cast(float, d[4*c+0]);
            q[1] = __builtin_bit_cast(float, d[4*c+1]);
            q[2] = __builtin_bit_cast(float, d[4*c+2]);
            q[3] = __builtin_bit_cast(float, d[4*c+3]);
            *(f32x4*)(rbase + (((unsigned)(c * 16)) ^ sw)) = q;
        }
        xt[slot]    = bpack(x[32], x[33]);
        rowid[slot] = (unsigned short)t;
    }
    __syncthreads();                 // xs/xt/rowid visible

    // ---- phase 3: MFMA + bf16 staged transpose; 2 lgkm barriers/tile ----
    const int wv   = t >> 6;
    const int lane = t & 63;
    const int r    = lane & 15;
    const int g    = lane >> 4;
    const int colbase = wv * 64 + r;
    const float NEG = -1e9f;
    const i32x4 mq = *(const i32x4*)(mask + 4 * lane);

    float* outb = out + (size_t)s0 * ACOL;

    for (int e2 = 0; e2 < NEXP; ++e2) {
        const int ntiles = ntl[e2];
        if (ntiles == 0) continue;

        // coalesced W fragments + per-lane store-side bias
        short8   bf1[4];
        unsigned w2[4];
        const uint4* wp = wpack + ((size_t)(e2 * 4 + wv) * 4) * 64 + lane;
        #pragma unroll
        for (int j = 0; j < 4; ++j) {
            bf1[j] = __builtin_bit_cast(short8, wp[j * 64]);
            w2[j]  = (g == 0) ? w2p[e2 * ACOL + colbase + j * 16] : 0u;
        }
        const f32x4 bias4 = *(const f32x4*)(bout + e2 * ACOL + 4 * lane);

        const int tb = goff[e2];
        for (int st = 0; st < ntiles; ++st) {
            const int rb  = tb + (st << 4);
            const int row = rb + r;
            const unsigned sw = (((unsigned)row >> 2) & 3u) << 4;
            const char* rp = (const char*)xs + row * 64;
            short8 a1 = *(const short8*)(rp + (((unsigned)(g * 16)) ^ sw));
            short8 a2 = __builtin_bit_cast(short8,
                          make_uint4(g == 0 ? xt[row] : 0u, 0u, 0u, 0u));

            f32x4 acc[4];
            #pragma unroll
            for (int j = 0; j < 4; ++j) {
                f32x4 a = {0.f, 0.f, 0.f, 0.f};
                a = __builtin_amdgcn_mfma_f32_16x16x32_bf16(a1, bf1[j], a, 0, 0, 0);
                short8 b2 = __builtin_bit_cast(short8,
                              make_uint4(w2[j], 0u, 0u, 0u));
                a = __builtin_amdgcn_mfma_f32_16x16x32_bf16(a2, b2, a, 0, 0, 0);
                acc[j] = a;
            }

            BAR_LGKM();   // WAR: all waves' reads of previous tile's stgb done

            #pragma unroll
            for (int j = 0; j < 4; ++j) {
                const int c = colbase + 16 * j;
                #pragma unroll
                for (int i = 0; i < 4; ++i)
                    stgb[(g * 4 + i) * STGS + c] =
                        (unsigned short)bpack(acc[j][i], 0.0f);
            }

            BAR_LGKM();   // RAW: staging visible

            // wave stores 4 full 1KB rows: bf16->f32 + bias + mask, plain dwordx4
            #pragma unroll
            for (int q = 0; q < 4; ++q) {
                const int lrow = wv * 4 + q;
                const unsigned rid = rowid[rb + lrow];
                const uint2 du = *(const uint2*)&stgb[lrow * STGS + 4 * lane];
                f32x4 v;
                v[0] = __builtin_bit_cast(float, du.x << 16)        + bias4[0];
                v[1] = __builtin_bit_cast(float, du.x & 0xffff0000u) + bias4[1];
                v[2] = __builtin_bit_cast(float, du.y << 16)        + bias4[2];
                v[3] = __builtin_bit_cast(float, du.y & 0xffff0000u) + bias4[3];
                v[0] = mq[0] ? v[0] : NEG;
                v[1] = mq[1] ? v[1] : NEG;
                v[2] = mq[2] ? v[2] : NEG;
                v[3] = mq[3] ? v[3] : NEG;
                if (rid != 0xFFFFu)
                    *(f32x4*)(outb + (size_t)rid * ACOL + 4 * lane) = v;
            }
        }
    }
}

extern "C" void kernel_launch(void* const* d_in, const int* in_sizes, int n_in,
                              void* d_out, int out_size, void* d_ws, size_t ws_size,
                              hipStream_t stream) {
    const float* states    = (const float*)d_in[0];
    const int*   epoch_idx = (const int*)  d_in[1];
    const float* W1        = (const float*)d_in[2];
    const float* b1        = (const float*)d_in[3];
    const float* Wout      = (const float*)d_in[4];
    const float* bout      = (const float*)d_in[5];
    const int*   mask      = (const int*)  d_in[6];
    float*       out       = (float*)d_out;

    const int nB   = in_sizes[0] / SDIM;
    const int grid = (nB + SPB - 1) / SPB;

    uint4*        wpack = (uint4*)d_ws;                          // 196608 B
    unsigned int* w2p   = (unsigned int*)((char*)d_ws + 196608); // 12288 B

    k0_wpack<<<48, 256, 0, stream>>>(Wout, wpack, w2p);
    actor_kernel<<<grid, 256, 0, stream>>>(states, epoch_idx, W1, b1,
                                           wpack, w2p, bout, mask, out, nB);
}